// Round 21
// baseline (244.749 us; speedup 1.0000x reference)
//
#include <hip/hip_runtime.h>
#include <hip/hip_cooperative_groups.h>
#include <stdint.h>

namespace cg = cooperative_groups;

#define NP 100000
#define NTASK (NP / 2)            // 50000 wave-tasks, 2 pillars each
#define MP 32
#define OC 64
#define GRID1 1024                // cooperative grid: 4 blocks/CU
#define NWAVES (GRID1 * 4)        // 4096
#define MAXK 13                   // ceil(NTASK / NWAVES)
#define BNEPS 0.001f
#define MTOT 3200000.0
#define PSTRIDE 144               // per-block partials: S[64] Q[64] G[10] pad

typedef short bf16x8 __attribute__((ext_vector_type(8)));
typedef float f32x16 __attribute__((ext_vector_type(16)));

union FRAG { uint32_t u[4]; bf16x8 v; };

__device__ __forceinline__ uint32_t pkbf16(float lo, float hi) {
    uint32_t r;
    asm("v_cvt_pk_bf16_f32 %0, %1, %2" : "=v"(r) : "v"(lo), "v"(hi));
    return r;
}

// fp32 bias -> bf16 hi + bf16 lo residual, packed (k4=hi, k5=lo)
__device__ __forceinline__ uint32_t biasPack(float b) {
    const uint32_t h = pkbf16(b, b) & 0xFFFFu;
    const float hf = __int_as_float(h << 16);
    return pkbf16(hf, b - hf);
}

__device__ __forceinline__ float red32(float v) {
    v += __int_as_float(__builtin_amdgcn_update_dpp(0, __float_as_int(v), 0xB1,  0xF, 0xF, true));
    v += __int_as_float(__builtin_amdgcn_update_dpp(0, __float_as_int(v), 0x4E,  0xF, 0xF, true));
    v += __int_as_float(__builtin_amdgcn_update_dpp(0, __float_as_int(v), 0x141, 0xF, 0xF, true));
    v += __int_as_float(__builtin_amdgcn_update_dpp(0, __float_as_int(v), 0x140, 0xF, 0xF, true));
    v += __int_as_float(__builtin_amdgcn_ds_swizzle(__float_as_int(v), 0x401F));
    return v;
}

__device__ __forceinline__ float max16(f32x16 d) {
    const float m0 = fmaxf(fmaxf(d[0], d[1]), d[2]);
    const float m1 = fmaxf(fmaxf(d[3], d[4]), d[5]);
    const float m2 = fmaxf(fmaxf(d[6], d[7]), d[8]);
    const float m3 = fmaxf(fmaxf(d[9], d[10]), d[11]);
    const float m4 = fmaxf(fmaxf(d[12], d[13]), d[14]);
    const float m5 = fmaxf(fmaxf(m0, m1), d[15]);
    const float m6 = fmaxf(fmaxf(m2, m3), m4);
    return fmaxf(m5, m6);
}

// ===========================================================================
// Shared r19 task body as a macro-free inline: computes per-task maxima mA,mB
// and accumulates stats. Used by both the fused and the fallback pass1.
// ===========================================================================
struct TaskCtx {
    uint32_t B0u0, B0u1, B1u0, B1u1;
    float w2[4], wcl[3], wce[3], sgn;
};

__device__ __forceinline__ void task_body(
    const TaskCtx& cx, const float4 curv, const int tu,
    const int* __restrict__ nump, const int* __restrict__ coors,
    const int lane, const bool hiHalf, const int pi,
    float& mA, float& mB, float& accS, float& accQ,
    float* g)
{
    const int nA = 2 * tu, nB = nA + 1;
    const int cntA = nump[nA], cntB = nump[nB];
    const int izA = coors[4*nA+1], iyA = coors[4*nA+2], ixA = coors[4*nA+3];
    const int izB = coors[4*nB+1], iyB = coors[4*nB+2], ixB = coors[4*nB+3];

    const int  myCnt = hiHalf ? cntB : cntA;
    const bool act = pi < myCnt;
    const float mx = act ? curv.x : 0.0f, my = act ? curv.y : 0.0f;
    const float mz = act ? curv.z : 0.0f, mw = act ? curv.w : 0.0f;

    g[0] = fmaf(mx, mx, g[0]); g[1] = fmaf(my, my, g[1]); g[2] = fmaf(mz, mz, g[2]);
    g[3] = fmaf(mw, mw, g[3]); g[4] = fmaf(mx, my, g[4]); g[5] = fmaf(mx, mz, g[5]);
    g[6] = fmaf(mx, mw, g[6]); g[7] = fmaf(my, mz, g[7]); g[8] = fmaf(my, mw, g[8]);
    g[9] = fmaf(mz, mw, g[9]);

    float s0 = red32(mx), s1 = red32(my), s2 = red32(mz), s3 = red32(mw);
    const float o0 = __shfl_xor(s0, 32, 64), o1 = __shfl_xor(s1, 32, 64);
    const float o2 = __shfl_xor(s2, 32, 64), o3 = __shfl_xor(s3, 32, 64);
    const float SA0 = hiHalf ? o0 : s0, SA1 = hiHalf ? o1 : s1;
    const float SA2 = hiHalf ? o2 : s2, SA3 = hiHalf ? o3 : s3;
    const float SB0 = hiHalf ? s0 : o0, SB1 = hiHalf ? s1 : o1;
    const float SB2 = hiHalf ? s2 : o2, SB3 = hiHalf ? s3 : o3;

    const float fcA = (float)cntA, rcA = __builtin_amdgcn_rcpf(fcA);
    const float fcB = (float)cntB, rcB = __builtin_amdgcn_rcpf(fcB);
    const float czA = ((float)izA + 0.5f) * 0.2f;
    const float cyA = ((float)iyA + 0.5f) * 0.2f;
    const float cxA = ((float)ixA + 0.5f) * 4.0f;
    const float czB = ((float)izB + 0.5f) * 0.2f;
    const float cyB = ((float)iyB + 0.5f) * 0.2f;
    const float cxB = ((float)ixB + 0.5f) * 4.0f;
    const float mtA   = fmaf(SA2, cx.wcl[2], fmaf(SA1, cx.wcl[1], SA0 * cx.wcl[0]));
    const float biasA = -fmaf(mtA, rcA, fmaf(czA, cx.wce[0], fmaf(cyA, cx.wce[1], cxA * cx.wce[2])));
    const float mtB   = fmaf(SB2, cx.wcl[2], fmaf(SB1, cx.wcl[1], SB0 * cx.wcl[0]));
    const float biasB = -fmaf(mtB, rcB, fmaf(czB, cx.wce[0], fmaf(cyB, cx.wce[1], cxB * cx.wce[2])));

    const uint32_t pkA = biasPack(biasA);
    const uint32_t pkB = biasPack(biasB);
    const uint32_t pkAo = (uint32_t)__shfl_xor((int)pkA, 32, 64);
    const uint32_t pkBo = (uint32_t)__shfl_xor((int)pkB, 32, 64);

    const uint32_t one2 = act ? 0x3F803F80u : 0u;
    const uint32_t one2o = (uint32_t)__shfl_xor((int)one2, 32, 64);
    const uint32_t pk0 = pkbf16(mx, my), pk1 = pkbf16(mz, mw);
    const uint32_t qk0 = (uint32_t)__shfl_xor((int)pk0, 32, 64);
    const uint32_t qk1 = (uint32_t)__shfl_xor((int)pk1, 32, 64);
    FRAG AA, AB;
    AA.u[0] = hiHalf ? 0u : pk0; AA.u[1] = hiHalf ? 0u : pk1;
    AA.u[2] = hiHalf ? 0u : one2; AA.u[3] = 0u;
    AB.u[0] = hiHalf ? 0u : qk0; AB.u[1] = hiHalf ? 0u : qk1;
    AB.u[2] = hiHalf ? 0u : one2o; AB.u[3] = 0u;

    FRAG B0A, B1A, B0B, B1B;
    B0A.u[0] = cx.B0u0; B0A.u[1] = cx.B0u1; B0A.u[2] = hiHalf ? 0u : pkA;  B0A.u[3] = 0u;
    B1A.u[0] = cx.B1u0; B1A.u[1] = cx.B1u1; B1A.u[2] = hiHalf ? 0u : pkAo; B1A.u[3] = 0u;
    B0B.u[0] = cx.B0u0; B0B.u[1] = cx.B0u1; B0B.u[2] = hiHalf ? 0u : pkB;  B0B.u[3] = 0u;
    B1B.u[0] = cx.B1u0; B1B.u[1] = cx.B1u1; B1B.u[2] = hiHalf ? 0u : pkBo; B1B.u[3] = 0u;

    const f32x16 CZ = {};
    f32x16 D;
    D = __builtin_amdgcn_mfma_f32_32x32x16_bf16(AA.v, B0A.v, CZ, 0, 0, 0);
    float mA0 = max16(D);
    D = __builtin_amdgcn_mfma_f32_32x32x16_bf16(AA.v, B1A.v, CZ, 0, 0, 0);
    float mA1 = max16(D);
    D = __builtin_amdgcn_mfma_f32_32x32x16_bf16(AB.v, B0B.v, CZ, 0, 0, 0);
    float mB0 = max16(D);
    D = __builtin_amdgcn_mfma_f32_32x32x16_bf16(AB.v, B1B.v, CZ, 0, 0, 0);
    float mB1 = max16(D);

    mA0 = fmaxf(mA0, __shfl_xor(mA0, 32, 64));
    mA1 = fmaxf(mA1, __shfl_xor(mA1, 32, 64));
    mB0 = fmaxf(mB0, __shfl_xor(mB0, 32, 64));
    mB1 = fmaxf(mB1, __shfl_xor(mB1, 32, 64));
    mA = hiHalf ? mA1 : mA0;
    mB = hiHalf ? mB1 : mB0;

    {
        const float ssum = fmaf(SA3, cx.w2[3], fmaf(SA2, cx.w2[2], fmaf(SA1, cx.w2[1], SA0 * cx.w2[0])));
        const float fb = fcA * biasA;
        accS = fmaf(cx.sgn, ssum + fb, accS);
        accQ += fmaf(fb, biasA, (biasA + biasA) * ssum);
    }
    {
        const float ssum = fmaf(SB3, cx.w2[3], fmaf(SB2, cx.w2[2], fmaf(SB1, cx.w2[1], SB0 * cx.w2[0])));
        const float fb = fcB * biasB;
        accS = fmaf(cx.sgn, ssum + fb, accS);
        accQ += fmaf(fb, biasB, (biasB + biasB) * ssum);
    }
}

__device__ __forceinline__ TaskCtx make_ctx(const float* __restrict__ W,
                                            const float* __restrict__ gamma,
                                            const int c, const bool hiHalf)
{
    TaskCtx cx;
    cx.w2[3] = W[3 * OC + c];
    #pragma unroll
    for (int k = 0; k < 3; ++k) {
        cx.wcl[k] = W[(4 + k) * OC + c];
        cx.wce[k] = W[(7 + k) * OC + c];
        cx.w2[k]  = W[k * OC + c] + cx.wcl[k] + cx.wce[k];
    }
    cx.sgn = (gamma[c] >= 0.0f) ? 1.0f : -1.0f;
    #pragma unroll
    for (int k = 0; k < 3; ++k) { cx.wcl[k] *= cx.sgn; cx.wce[k] *= cx.sgn; cx.w2[k] *= cx.sgn; }
    cx.w2[3] *= cx.sgn;
    const uint32_t bw0 = pkbf16(cx.w2[0], cx.w2[1]);
    const uint32_t bw1 = pkbf16(cx.w2[2], cx.w2[3]);
    const uint32_t ob0 = (uint32_t)__shfl_xor((int)bw0, 32, 64);
    const uint32_t ob1 = (uint32_t)__shfl_xor((int)bw1, 32, 64);
    cx.B0u0 = hiHalf ? 0u : bw0; cx.B0u1 = hiHalf ? 0u : bw1;
    cx.B1u0 = hiHalf ? 0u : ob0; cx.B1u1 = hiHalf ? 0u : ob1;
    return cx;
}

// block-level stats reduction -> partials row (shared helper)
__device__ __forceinline__ void store_partials(
    float accS, float accQ, float* g, float (*sred)[128], float (*sredG)[10],
    const int wid, const int lane, float* __restrict__ row)
{
    sred[wid][lane]      = accS;
    sred[wid][64 + lane] = accQ;
    #pragma unroll
    for (int k = 0; k < 10; ++k) {
        float v = red32(g[k]);
        v += __shfl_xor(v, 32, 64);
        g[k] = v;
    }
    if (lane == 0) {
        #pragma unroll
        for (int k = 0; k < 10; ++k) sredG[wid][k] = g[k];
    }
    __syncthreads();
    if (wid == 0) {
        row[lane]      = sred[0][lane] + sred[1][lane] + sred[2][lane] + sred[3][lane];
        row[64 + lane] = sred[0][64+lane] + sred[1][64+lane] + sred[2][64+lane] + sred[3][64+lane];
        if (lane < 10)
            row[128 + lane] = sredG[0][lane] + sredG[1][lane] + sredG[2][lane] + sredG[3][lane];
        if (lane >= 10 && lane < 16) row[128 + lane] = 0.0f;
    }
}

// fp64 finalize from summed stats -> (sc, sh) for channel c
__device__ __forceinline__ void finalize_ch(const float* stats,
                                            const float* __restrict__ W,
                                            const float* __restrict__ gamma,
                                            const float* __restrict__ beta,
                                            const int c, float& scv, float& shv)
{
    double G[10];
    #pragma unroll
    for (int k = 0; k < 10; ++k) G[k] = (double)stats[128 + k];
    double w[4];
    w[3] = (double)W[3 * OC + c];
    #pragma unroll
    for (int k = 0; k < 3; ++k)
        w[k] = (double)W[k * OC + c] + (double)W[(4 + k) * OC + c] + (double)W[(7 + k) * OC + c];
    const double q = w[0]*w[0]*G[0] + w[1]*w[1]*G[1] + w[2]*w[2]*G[2] + w[3]*w[3]*G[3]
        + 2.0 * (w[0]*w[1]*G[4] + w[0]*w[2]*G[5] + w[0]*w[3]*G[6]
               + w[1]*w[2]*G[7] + w[1]*w[3]*G[8] + w[2]*w[3]*G[9]);
    const double S  = (double)stats[c];
    const double Qb = (double)stats[64 + c];
    const double mu_d  = S / MTOT;
    const double var_d = (q + Qb) / MTOT - mu_d * mu_d;
    scv = gamma[c] * rsqrtf((float)var_d + BNEPS);
    shv = beta[c] - (float)mu_d * scv;
}

// ===========================================================================
// FUSED cooperative kernel. LDS kept under 16 KB (bf16 msave + union overlay)
// so cooperative occupancy validation passes even under a 64 KB/CU assumption.
// ===========================================================================
__global__ __launch_bounds__(256, 4) void sap_fused(
    const float* __restrict__ feat, const float* __restrict__ W,
    const float* __restrict__ gamma, const float* __restrict__ beta,
    const int* __restrict__ nump, const int* __restrict__ coors,
    float* __restrict__ out, float* __restrict__ partials,
    float* __restrict__ partials2)
{
    __shared__ unsigned short msave[2 * MAXK][256];   // 13.3 KB (bf16 maxima)
    __shared__ union {
        struct { float sred[4][128]; float sredG[4][10]; } p1;   // 2.2 KB
        float stats[PSTRIDE];
    } sh;
    const int tid  = threadIdx.x;
    const int lane = tid & 63;
    const int wid  = tid >> 6;
    const int c = lane;
    const int pi = lane & 31;
    const bool hiHalf = lane >= 32;

    const TaskCtx cx = make_ctx(W, gamma, c, hiHalf);
    const float4* __restrict__ feat4 = reinterpret_cast<const float4*>(feat);

    float accS = 0.0f, accQ = 0.0f;
    float g[10];
    #pragma unroll
    for (int k = 0; k < 10; ++k) g[k] = 0.0f;

    const int base = blockIdx.x * 4 + wid;
    float4 curv = feat4[(size_t)base * 64 + lane];

    #pragma unroll 1
    for (int k = 0; k < MAXK; ++k) {
        const int t = base + k * NWAVES;
        if (t >= NTASK) break;
        const int tu = __builtin_amdgcn_readfirstlane(t);
        const int tn = t + NWAVES;
        float4 nxtv = curv;
        if (tn < NTASK) nxtv = feat4[(size_t)tn * 64 + lane];
        float mA, mB;
        task_body(cx, curv, tu, nump, coors, lane, hiHalf, pi, mA, mB, accS, accQ, g);
        msave[2 * k][tid]     = (unsigned short)(pkbf16(mA, mA) & 0xFFFFu);
        msave[2 * k + 1][tid] = (unsigned short)(pkbf16(mB, mB) & 0xFFFFu);
        curv = nxtv;
    }

    store_partials(accS, accQ, g, sh.p1.sred, sh.p1.sredG, wid, lane,
                   partials + (size_t)blockIdx.x * PSTRIDE);

    cg::this_grid().sync();

    if (blockIdx.x < 64 && tid < PSTRIDE) {
        float s = 0.0f;
        for (int b = blockIdx.x; b < GRID1; b += 64)
            s += partials[(size_t)b * PSTRIDE + tid];
        partials2[(size_t)blockIdx.x * PSTRIDE + tid] = s;
    }

    cg::this_grid().sync();

    if (tid < PSTRIDE) {
        float s = 0.0f;
        #pragma unroll
        for (int b = 0; b < 64; ++b)
            s += partials2[(size_t)b * PSTRIDE + tid];
        sh.stats[tid] = s;
    }
    __syncthreads();

    float scv, shv;
    finalize_ch(sh.stats, W, gamma, beta, c, scv, shv);
    const float scs = scv * cx.sgn;     // m stored as sgn-less max of h'

    #pragma unroll 1
    for (int k = 0; k < MAXK; ++k) {
        const int t = base + k * NWAVES;
        if (t >= NTASK) break;
        const float mA = __int_as_float(((uint32_t)msave[2 * k][tid]) << 16);
        const float mB = __int_as_float(((uint32_t)msave[2 * k + 1][tid]) << 16);
        out[(size_t)(2 * t)     * OC + c] = fmaxf(fmaf(scs, mA, shv), 0.0f);
        out[(size_t)(2 * t + 1) * OC + c] = fmaxf(fmaf(scs, mB, shv), 0.0f);
    }
}

// ===========================================================================
// FALLBACK: r19 four-kernel pipeline (proven, 53 us).
// ===========================================================================
__global__ __launch_bounds__(256) void sap_pass1(
    const float* __restrict__ feat, const float* __restrict__ W,
    const float* __restrict__ gamma, const int* __restrict__ nump,
    const int* __restrict__ coors, float* __restrict__ hsel,
    float* __restrict__ partials, const int nwaves)
{
    __shared__ float sred[4][128];
    __shared__ float sredG[4][10];
    const int lane = threadIdx.x & 63;
    const int wid  = threadIdx.x >> 6;
    const int c = lane;
    const int pi = lane & 31;
    const bool hiHalf = lane >= 32;

    const TaskCtx cx = make_ctx(W, gamma, c, hiHalf);
    const float4* __restrict__ feat4 = reinterpret_cast<const float4*>(feat);

    float accS = 0.0f, accQ = 0.0f;
    float g[10];
    #pragma unroll
    for (int k = 0; k < 10; ++k) g[k] = 0.0f;

    int t = blockIdx.x * 4 + wid;
    float4 curv = feat4[(size_t)t * 64 + lane];

    for (; t < NTASK; t += nwaves) {
        const int tu = __builtin_amdgcn_readfirstlane(t);
        const int tn = t + nwaves;
        float4 nxtv = curv;
        if (tn < NTASK) nxtv = feat4[(size_t)tn * 64 + lane];
        float mA, mB;
        task_body(cx, curv, tu, nump, coors, lane, hiHalf, pi, mA, mB, accS, accQ, g);
        hsel[(size_t)(2 * tu)     * OC + c] = cx.sgn * mA;
        hsel[(size_t)(2 * tu + 1) * OC + c] = cx.sgn * mB;
        curv = nxtv;
    }

    store_partials(accS, accQ, g, sred, sredG, wid, lane,
                   partials + (size_t)blockIdx.x * PSTRIDE);
}

__global__ __launch_bounds__(256) void sap_reduce1(const float* __restrict__ partials,
                                                   float* __restrict__ partials2,
                                                   const int nrows)
{
    const int col = threadIdx.x;
    if (col >= PSTRIDE) return;
    const int gb = blockIdx.x;
    float s = 0.0f;
    for (int b = gb; b < nrows; b += 64)
        s += partials[(size_t)b * PSTRIDE + col];
    partials2[(size_t)gb * PSTRIDE + col] = s;
}

__global__ void sap_finalize(const float* __restrict__ partials2,
                             const float* __restrict__ W,
                             const float* __restrict__ gamma,
                             const float* __restrict__ beta,
                             float* __restrict__ scsh)
{
    __shared__ float stats[PSTRIDE];
    const int tid = threadIdx.x;
    if (tid < PSTRIDE) {
        float s = 0.0f;
        #pragma unroll
        for (int b = 0; b < 64; ++b)
            s += partials2[(size_t)b * PSTRIDE + tid];
        stats[tid] = s;
    }
    __syncthreads();
    if (tid >= 64) return;
    float scv, shv;
    finalize_ch(stats, W, gamma, beta, tid, scv, shv);
    scsh[tid]      = scv;
    scsh[64 + tid] = shv;
}

__global__ __launch_bounds__(256) void sap_pass2(const float* __restrict__ scsh,
                                                 float* __restrict__ out)
{
    const int idx = blockIdx.x * 256 + threadIdx.x;
    if (idx >= (NP * OC) / 4) return;
    float4 h = reinterpret_cast<float4*>(out)[idx];
    const int ci = idx & 15;
    const float4 sc = reinterpret_cast<const float4*>(scsh)[ci];
    const float4 shf = reinterpret_cast<const float4*>(scsh + 64)[ci];
    float4 o;
    o.x = fmaxf(fmaf(h.x, sc.x, shf.x), 0.0f);
    o.y = fmaxf(fmaf(h.y, sc.y, shf.y), 0.0f);
    o.z = fmaxf(fmaf(h.z, sc.z, shf.z), 0.0f);
    o.w = fmaxf(fmaf(h.w, sc.w, shf.w), 0.0f);
    reinterpret_cast<float4*>(out)[idx] = o;
}

extern "C" void kernel_launch(void* const* d_in, const int* in_sizes, int n_in,
                              void* d_out, int out_size, void* d_ws, size_t ws_size,
                              hipStream_t stream) {
    const float* feat  = (const float*)d_in[0];
    const float* W     = (const float*)d_in[1];
    const float* gamma = (const float*)d_in[2];
    const float* beta  = (const float*)d_in[3];
    const int*   nump  = (const int*)d_in[4];
    const int*   coors = (const int*)d_in[5];
    float* out = (float*)d_out;

    float* partials  = (float*)d_ws;                            // 2048*144*4 max
    float* partials2 = partials + (size_t)2048 * PSTRIDE;       // 64*144*4
    float* scsh      = partials2 + 64 * PSTRIDE;                // 512 B

    void* args[] = { (void*)&feat, (void*)&W, (void*)&gamma, (void*)&beta,
                     (void*)&nump, (void*)&coors, (void*)&out,
                     (void*)&partials, (void*)&partials2 };
    hipError_t err = hipLaunchCooperativeKernel((const void*)sap_fused,
                                                dim3(GRID1), dim3(256),
                                                args, 0, stream);
    if (err != hipSuccess) {
        // fallback: proven r19 pipeline
        const int grid1 = 2048;
        sap_pass1<<<grid1, 256, 0, stream>>>(
            feat, W, gamma, nump, coors, out, partials, grid1 * 4);
        sap_reduce1<<<64, 256, 0, stream>>>(partials, partials2, grid1);
        sap_finalize<<<1, 256, 0, stream>>>(partials2, W, gamma, beta, scsh);
        sap_pass2<<<(NP * OC / 4 + 255) / 256, 256, 0, stream>>>(scsh, out);
    }
}

// Round 22
// 50.801 us; speedup vs baseline: 4.8178x; 4.8178x over previous
//
#include <hip/hip_runtime.h>
#include <stdint.h>

#define NP 100000
#define NTASK (NP / 2)            // 50000 wave-tasks, 2 pillars each
#define MP 32
#define OC 64
#define BNEPS 0.001f
#define MTOT 3200000.0
#define PSTRIDE 144               // per-block partials: S[64] Q[64] G[10] pad

typedef short bf16x8 __attribute__((ext_vector_type(8)));
typedef float f32x16 __attribute__((ext_vector_type(16)));

union FRAG { uint32_t u[4]; bf16x8 v; };

__device__ __forceinline__ uint32_t pkbf16(float lo, float hi) {
    uint32_t r;
    asm("v_cvt_pk_bf16_f32 %0, %1, %2" : "=v"(r) : "v"(lo), "v"(hi));
    return r;
}

// fp32 bias -> bf16 hi + bf16 lo residual, packed (k4=hi, k5=lo)
__device__ __forceinline__ uint32_t biasPack(float b) {
    const uint32_t h = pkbf16(b, b) & 0xFFFFu;
    const float hf = __int_as_float(h << 16);
    return pkbf16(hf, b - hf);
}

__device__ __forceinline__ float red32(float v) {
    v += __int_as_float(__builtin_amdgcn_update_dpp(0, __float_as_int(v), 0xB1,  0xF, 0xF, true));
    v += __int_as_float(__builtin_amdgcn_update_dpp(0, __float_as_int(v), 0x4E,  0xF, 0xF, true));
    v += __int_as_float(__builtin_amdgcn_update_dpp(0, __float_as_int(v), 0x141, 0xF, 0xF, true));
    v += __int_as_float(__builtin_amdgcn_update_dpp(0, __float_as_int(v), 0x140, 0xF, 0xF, true));
    v += __int_as_float(__builtin_amdgcn_ds_swizzle(__float_as_int(v), 0x401F));
    return v;
}

__device__ __forceinline__ float max16(f32x16 d) {
    const float m0 = fmaxf(fmaxf(d[0], d[1]), d[2]);
    const float m1 = fmaxf(fmaxf(d[3], d[4]), d[5]);
    const float m2 = fmaxf(fmaxf(d[6], d[7]), d[8]);
    const float m3 = fmaxf(fmaxf(d[9], d[10]), d[11]);
    const float m4 = fmaxf(fmaxf(d[12], d[13]), d[14]);
    const float m5 = fmaxf(fmaxf(m0, m1), d[15]);
    const float m6 = fmaxf(fmaxf(m2, m3), m4);
    return fmaxf(m5, m6);
}

struct TaskCtx {
    uint32_t B0u0, B0u1, B1u0, B1u1;
    float w2[4], wcl[3], wce[3], sgn;
};

__device__ __forceinline__ TaskCtx make_ctx(const float* __restrict__ W,
                                            const float* __restrict__ gamma,
                                            const int c, const bool hiHalf)
{
    TaskCtx cx;
    cx.w2[3] = W[3 * OC + c];
    #pragma unroll
    for (int k = 0; k < 3; ++k) {
        cx.wcl[k] = W[(4 + k) * OC + c];
        cx.wce[k] = W[(7 + k) * OC + c];
        cx.w2[k]  = W[k * OC + c] + cx.wcl[k] + cx.wce[k];
    }
    cx.sgn = (gamma[c] >= 0.0f) ? 1.0f : -1.0f;
    #pragma unroll
    for (int k = 0; k < 3; ++k) { cx.wcl[k] *= cx.sgn; cx.wce[k] *= cx.sgn; cx.w2[k] *= cx.sgn; }
    cx.w2[3] *= cx.sgn;
    const uint32_t bw0 = pkbf16(cx.w2[0], cx.w2[1]);
    const uint32_t bw1 = pkbf16(cx.w2[2], cx.w2[3]);
    const uint32_t ob0 = (uint32_t)__shfl_xor((int)bw0, 32, 64);
    const uint32_t ob1 = (uint32_t)__shfl_xor((int)bw1, 32, 64);
    cx.B0u0 = hiHalf ? 0u : bw0; cx.B0u1 = hiHalf ? 0u : bw1;
    cx.B1u0 = hiHalf ? 0u : ob0; cx.B1u1 = hiHalf ? 0u : ob1;
    return cx;
}

__device__ __forceinline__ void task_body(
    const TaskCtx& cx, const float4 curv, const int tu,
    const int* __restrict__ nump, const int* __restrict__ coors,
    const int lane, const bool hiHalf, const int pi,
    float& mA, float& mB, float& accS, float& accQ,
    float* g)
{
    const int nA = 2 * tu, nB = nA + 1;
    const int cntA = nump[nA], cntB = nump[nB];
    const int izA = coors[4*nA+1], iyA = coors[4*nA+2], ixA = coors[4*nA+3];
    const int izB = coors[4*nB+1], iyB = coors[4*nB+2], ixB = coors[4*nB+3];

    const int  myCnt = hiHalf ? cntB : cntA;
    const bool act = pi < myCnt;
    const float mx = act ? curv.x : 0.0f, my = act ? curv.y : 0.0f;
    const float mz = act ? curv.z : 0.0f, mw = act ? curv.w : 0.0f;

    g[0] = fmaf(mx, mx, g[0]); g[1] = fmaf(my, my, g[1]); g[2] = fmaf(mz, mz, g[2]);
    g[3] = fmaf(mw, mw, g[3]); g[4] = fmaf(mx, my, g[4]); g[5] = fmaf(mx, mz, g[5]);
    g[6] = fmaf(mx, mw, g[6]); g[7] = fmaf(my, mz, g[7]); g[8] = fmaf(my, mw, g[8]);
    g[9] = fmaf(mz, mw, g[9]);

    float s0 = red32(mx), s1 = red32(my), s2 = red32(mz), s3 = red32(mw);
    const float o0 = __shfl_xor(s0, 32, 64), o1 = __shfl_xor(s1, 32, 64);
    const float o2 = __shfl_xor(s2, 32, 64), o3 = __shfl_xor(s3, 32, 64);
    const float SA0 = hiHalf ? o0 : s0, SA1 = hiHalf ? o1 : s1;
    const float SA2 = hiHalf ? o2 : s2, SA3 = hiHalf ? o3 : s3;
    const float SB0 = hiHalf ? s0 : o0, SB1 = hiHalf ? s1 : o1;
    const float SB2 = hiHalf ? s2 : o2, SB3 = hiHalf ? s3 : o3;

    const float fcA = (float)cntA, rcA = __builtin_amdgcn_rcpf(fcA);
    const float fcB = (float)cntB, rcB = __builtin_amdgcn_rcpf(fcB);
    const float czA = ((float)izA + 0.5f) * 0.2f;
    const float cyA = ((float)iyA + 0.5f) * 0.2f;
    const float cxA = ((float)ixA + 0.5f) * 4.0f;
    const float czB = ((float)izB + 0.5f) * 0.2f;
    const float cyB = ((float)iyB + 0.5f) * 0.2f;
    const float cxB = ((float)ixB + 0.5f) * 4.0f;
    const float mtA   = fmaf(SA2, cx.wcl[2], fmaf(SA1, cx.wcl[1], SA0 * cx.wcl[0]));
    const float biasA = -fmaf(mtA, rcA, fmaf(czA, cx.wce[0], fmaf(cyA, cx.wce[1], cxA * cx.wce[2])));
    const float mtB   = fmaf(SB2, cx.wcl[2], fmaf(SB1, cx.wcl[1], SB0 * cx.wcl[0]));
    const float biasB = -fmaf(mtB, rcB, fmaf(czB, cx.wce[0], fmaf(cyB, cx.wce[1], cxB * cx.wce[2])));

    const uint32_t pkA = biasPack(biasA);
    const uint32_t pkB = biasPack(biasB);
    const uint32_t pkAo = (uint32_t)__shfl_xor((int)pkA, 32, 64);
    const uint32_t pkBo = (uint32_t)__shfl_xor((int)pkB, 32, 64);

    const uint32_t one2 = act ? 0x3F803F80u : 0u;
    const uint32_t one2o = (uint32_t)__shfl_xor((int)one2, 32, 64);
    const uint32_t pk0 = pkbf16(mx, my), pk1 = pkbf16(mz, mw);
    const uint32_t qk0 = (uint32_t)__shfl_xor((int)pk0, 32, 64);
    const uint32_t qk1 = (uint32_t)__shfl_xor((int)pk1, 32, 64);
    FRAG AA, AB;
    AA.u[0] = hiHalf ? 0u : pk0; AA.u[1] = hiHalf ? 0u : pk1;
    AA.u[2] = hiHalf ? 0u : one2; AA.u[3] = 0u;
    AB.u[0] = hiHalf ? 0u : qk0; AB.u[1] = hiHalf ? 0u : qk1;
    AB.u[2] = hiHalf ? 0u : one2o; AB.u[3] = 0u;

    FRAG B0A, B1A, B0B, B1B;
    B0A.u[0] = cx.B0u0; B0A.u[1] = cx.B0u1; B0A.u[2] = hiHalf ? 0u : pkA;  B0A.u[3] = 0u;
    B1A.u[0] = cx.B1u0; B1A.u[1] = cx.B1u1; B1A.u[2] = hiHalf ? 0u : pkAo; B1A.u[3] = 0u;
    B0B.u[0] = cx.B0u0; B0B.u[1] = cx.B0u1; B0B.u[2] = hiHalf ? 0u : pkB;  B0B.u[3] = 0u;
    B1B.u[0] = cx.B1u0; B1B.u[1] = cx.B1u1; B1B.u[2] = hiHalf ? 0u : pkBo; B1B.u[3] = 0u;

    const f32x16 CZ = {};
    f32x16 D;
    D = __builtin_amdgcn_mfma_f32_32x32x16_bf16(AA.v, B0A.v, CZ, 0, 0, 0);
    float mA0 = max16(D);
    D = __builtin_amdgcn_mfma_f32_32x32x16_bf16(AA.v, B1A.v, CZ, 0, 0, 0);
    float mA1 = max16(D);
    D = __builtin_amdgcn_mfma_f32_32x32x16_bf16(AB.v, B0B.v, CZ, 0, 0, 0);
    float mB0 = max16(D);
    D = __builtin_amdgcn_mfma_f32_32x32x16_bf16(AB.v, B1B.v, CZ, 0, 0, 0);
    float mB1 = max16(D);

    mA0 = fmaxf(mA0, __shfl_xor(mA0, 32, 64));
    mA1 = fmaxf(mA1, __shfl_xor(mA1, 32, 64));
    mB0 = fmaxf(mB0, __shfl_xor(mB0, 32, 64));
    mB1 = fmaxf(mB1, __shfl_xor(mB1, 32, 64));
    mA = hiHalf ? mA1 : mA0;
    mB = hiHalf ? mB1 : mB0;

    {
        const float ssum = fmaf(SA3, cx.w2[3], fmaf(SA2, cx.w2[2], fmaf(SA1, cx.w2[1], SA0 * cx.w2[0])));
        const float fb = fcA * biasA;
        accS = fmaf(cx.sgn, ssum + fb, accS);
        accQ += fmaf(fb, biasA, (biasA + biasA) * ssum);
    }
    {
        const float ssum = fmaf(SB3, cx.w2[3], fmaf(SB2, cx.w2[2], fmaf(SB1, cx.w2[1], SB0 * cx.w2[0])));
        const float fb = fcB * biasB;
        accS = fmaf(cx.sgn, ssum + fb, accS);
        accQ += fmaf(fb, biasB, (biasB + biasB) * ssum);
    }
}

__device__ __forceinline__ void store_partials(
    float accS, float accQ, float* g, float (*sred)[128], float (*sredG)[10],
    const int wid, const int lane, float* __restrict__ row)
{
    sred[wid][lane]      = accS;
    sred[wid][64 + lane] = accQ;
    #pragma unroll
    for (int k = 0; k < 10; ++k) {
        float v = red32(g[k]);
        v += __shfl_xor(v, 32, 64);
        g[k] = v;
    }
    if (lane == 0) {
        #pragma unroll
        for (int k = 0; k < 10; ++k) sredG[wid][k] = g[k];
    }
    __syncthreads();
    if (wid == 0) {
        row[lane]      = sred[0][lane] + sred[1][lane] + sred[2][lane] + sred[3][lane];
        row[64 + lane] = sred[0][64+lane] + sred[1][64+lane] + sred[2][64+lane] + sred[3][64+lane];
        if (lane < 10)
            row[128 + lane] = sredG[0][lane] + sredG[1][lane] + sredG[2][lane] + sredG[3][lane];
        if (lane >= 10 && lane < 16) row[128 + lane] = 0.0f;
    }
}

__device__ __forceinline__ void finalize_ch(const float* stats,
                                            const float* __restrict__ W,
                                            const float* __restrict__ gamma,
                                            const float* __restrict__ beta,
                                            const int c, float& scv, float& shv)
{
    double G[10];
    #pragma unroll
    for (int k = 0; k < 10; ++k) G[k] = (double)stats[128 + k];
    double w[4];
    w[3] = (double)W[3 * OC + c];
    #pragma unroll
    for (int k = 0; k < 3; ++k)
        w[k] = (double)W[k * OC + c] + (double)W[(4 + k) * OC + c] + (double)W[(7 + k) * OC + c];
    const double q = w[0]*w[0]*G[0] + w[1]*w[1]*G[1] + w[2]*w[2]*G[2] + w[3]*w[3]*G[3]
        + 2.0 * (w[0]*w[1]*G[4] + w[0]*w[2]*G[5] + w[0]*w[3]*G[6]
               + w[1]*w[2]*G[7] + w[1]*w[3]*G[8] + w[2]*w[3]*G[9]);
    const double S  = (double)stats[c];
    const double Qb = (double)stats[64 + c];
    const double mu_d  = S / MTOT;
    const double var_d = (q + Qb) / MTOT - mu_d * mu_d;
    scv = gamma[c] * rsqrtf((float)var_d + BNEPS);
    shv = beta[c] - (float)mu_d * scv;
}

// ---------------------------------------------------------------------------
// Pass 1 (r19 body): maxima stored as bf16 into d_ws (halves round-trip BW).
// hselb holds sgn-less m (h' max); sgn folded into pass2's scale.
// ---------------------------------------------------------------------------
__global__ __launch_bounds__(256) void sap_pass1(
    const float* __restrict__ feat, const float* __restrict__ W,
    const float* __restrict__ gamma, const int* __restrict__ nump,
    const int* __restrict__ coors, unsigned short* __restrict__ hselb,
    float* __restrict__ partials, const int nwaves)
{
    __shared__ float sred[4][128];
    __shared__ float sredG[4][10];
    const int lane = threadIdx.x & 63;
    const int wid  = threadIdx.x >> 6;
    const int c = lane;
    const int pi = lane & 31;
    const bool hiHalf = lane >= 32;

    const TaskCtx cx = make_ctx(W, gamma, c, hiHalf);
    const float4* __restrict__ feat4 = reinterpret_cast<const float4*>(feat);

    float accS = 0.0f, accQ = 0.0f;
    float g[10];
    #pragma unroll
    for (int k = 0; k < 10; ++k) g[k] = 0.0f;

    int t = blockIdx.x * 4 + wid;
    float4 curv = feat4[(size_t)t * 64 + lane];

    for (; t < NTASK; t += nwaves) {
        const int tu = __builtin_amdgcn_readfirstlane(t);
        const int tn = t + nwaves;
        float4 nxtv = curv;
        if (tn < NTASK) nxtv = feat4[(size_t)tn * 64 + lane];
        float mA, mB;
        task_body(cx, curv, tu, nump, coors, lane, hiHalf, pi, mA, mB, accS, accQ, g);
        hselb[(size_t)(2 * tu)     * OC + c] = (unsigned short)(pkbf16(mA, mA) & 0xFFFFu);
        hselb[(size_t)(2 * tu + 1) * OC + c] = (unsigned short)(pkbf16(mB, mB) & 0xFFFFu);
        curv = nxtv;
    }

    store_partials(accS, accQ, g, sred, sredG, wid, lane,
                   partials + (size_t)blockIdx.x * PSTRIDE);
}

__global__ __launch_bounds__(256) void sap_reduce1(const float* __restrict__ partials,
                                                   float* __restrict__ partials2,
                                                   const int nrows)
{
    const int col = threadIdx.x;
    if (col >= PSTRIDE) return;
    const int gb = blockIdx.x;
    float s = 0.0f;
    for (int b = gb; b < nrows; b += 64)
        s += partials[(size_t)b * PSTRIDE + col];
    partials2[(size_t)gb * PSTRIDE + col] = s;
}

// scsh layout: [0..63] = sc*sgn (applied to sgn-less m), [64..127] = sh
__global__ void sap_finalize(const float* __restrict__ partials2,
                             const float* __restrict__ W,
                             const float* __restrict__ gamma,
                             const float* __restrict__ beta,
                             float* __restrict__ scsh)
{
    __shared__ float stats[PSTRIDE];
    const int tid = threadIdx.x;
    if (tid < PSTRIDE) {
        float s = 0.0f;
        #pragma unroll
        for (int b = 0; b < 64; ++b)
            s += partials2[(size_t)b * PSTRIDE + tid];
        stats[tid] = s;
    }
    __syncthreads();
    if (tid >= 64) return;
    float scv, shv;
    finalize_ch(stats, W, gamma, beta, tid, scv, shv);
    const float sgn = (gamma[tid] >= 0.0f) ? 1.0f : -1.0f;
    scsh[tid]      = scv * sgn;
    scsh[64 + tid] = shv;
}

// ---------------------------------------------------------------------------
// Pass 2: read bf16 maxima (8 per thread), apply scale/shift, write fp32 out.
// ---------------------------------------------------------------------------
__global__ __launch_bounds__(256) void sap_pass2(const unsigned short* __restrict__ hselb,
                                                 const float* __restrict__ scsh,
                                                 float* __restrict__ out)
{
    const int idx = blockIdx.x * 256 + threadIdx.x;
    if (idx >= (NP * OC) / 8) return;
    const uint4 hv = reinterpret_cast<const uint4*>(hselb)[idx];
    const int cb = (idx & 7) * 8;                      // channel base (64ch/8)
    const float4 scL = *reinterpret_cast<const float4*>(scsh + cb);
    const float4 scH = *reinterpret_cast<const float4*>(scsh + cb + 4);
    const float4 shL = *reinterpret_cast<const float4*>(scsh + 64 + cb);
    const float4 shH = *reinterpret_cast<const float4*>(scsh + 64 + cb + 4);
    float4 o0, o1;
    o0.x = fmaxf(fmaf(__int_as_float(hv.x << 16),        scL.x, shL.x), 0.0f);
    o0.y = fmaxf(fmaf(__int_as_float(hv.x & 0xFFFF0000), scL.y, shL.y), 0.0f);
    o0.z = fmaxf(fmaf(__int_as_float(hv.y << 16),        scL.z, shL.z), 0.0f);
    o0.w = fmaxf(fmaf(__int_as_float(hv.y & 0xFFFF0000), scL.w, shL.w), 0.0f);
    o1.x = fmaxf(fmaf(__int_as_float(hv.z << 16),        scH.x, shH.x), 0.0f);
    o1.y = fmaxf(fmaf(__int_as_float(hv.z & 0xFFFF0000), scH.y, shH.y), 0.0f);
    o1.z = fmaxf(fmaf(__int_as_float(hv.w << 16),        scH.z, shH.z), 0.0f);
    o1.w = fmaxf(fmaf(__int_as_float(hv.w & 0xFFFF0000), scH.w, shH.w), 0.0f);
    reinterpret_cast<float4*>(out)[idx * 2]     = o0;
    reinterpret_cast<float4*>(out)[idx * 2 + 1] = o1;
}

extern "C" void kernel_launch(void* const* d_in, const int* in_sizes, int n_in,
                              void* d_out, int out_size, void* d_ws, size_t ws_size,
                              hipStream_t stream) {
    const float* feat  = (const float*)d_in[0];
    const float* W     = (const float*)d_in[1];
    const float* gamma = (const float*)d_in[2];
    const float* beta  = (const float*)d_in[3];
    const int*   nump  = (const int*)d_in[4];
    const int*   coors = (const int*)d_in[5];
    float* out = (float*)d_out;

    unsigned short* hselb = (unsigned short*)d_ws;                 // 12.8 MB
    float* partials  = (float*)((char*)d_ws + (size_t)NP * OC * 2);
    float* partials2 = partials + (size_t)2048 * PSTRIDE;
    float* scsh      = partials2 + 64 * PSTRIDE;

    const int grid1 = 2048;
    sap_pass1<<<grid1, 256, 0, stream>>>(
        feat, W, gamma, nump, coors, hselb, partials, grid1 * 4);
    sap_reduce1<<<64, 256, 0, stream>>>(partials, partials2, grid1);
    sap_finalize<<<1, 256, 0, stream>>>(partials2, W, gamma, beta, scsh);
    sap_pass2<<<(NP * OC / 8 + 255) / 256, 256, 0, stream>>>(hselb, scsh, out);
}